// Round 4
// baseline (4185.847 us; speedup 1.0000x reference)
//
#include <hip/hip_runtime.h>
#include <type_traits>
#include <cstdint>
#include <cstddef>

#define L_SEQ 4800
#define DMODEL 256
#define BS 8
#define MROWS (BS*L_SEQ)          // 38400
#define PERBATCH (L_SEQ*DMODEL)   // 1228800
#define KVSET 67584               // 65536 KV + 2048 Ksum floats per mode

// ---------- helpers ----------
__device__ __forceinline__ float bf2f(unsigned short u){
  union { unsigned int i; float f; } x; x.i = ((unsigned int)u) << 16; return x.f;
}
__device__ __forceinline__ unsigned short f2bf(float f){
  union { float f; unsigned int i; } x; x.f = f;
  x.i += 0x7fff + ((x.i >> 16) & 1);   // RNE
  return (unsigned short)(x.i >> 16);
}
// phi(x) = elu(x) + 1
__device__ __forceinline__ float phi(float x){
  return x > 0.f ? x + 1.f : __expf(x);
}

// permuted (l,g) -> original flat index within one batch's [4800*256] buffer
template<int MODE>
__device__ __forceinline__ int perm_src(int l, int g){
  if constexpr (MODE == 0){
    return l*256 + g;
  } else if constexpr (MODE == 1){        // p13: per-token [8,32]->[32,8] transpose view
    return l*256 + ((g & 7) << 5) + (g >> 3);
  } else if constexpr (MODE == 2){        // p21: [h,L,dh] flattened
    int F = l*256 + g;
    int i = F / 153600;                   // L*32
    int r = F - i*153600;
    return ((r >> 5) << 8) + (i << 5) + (r & 31);
  } else {                                // p32: [dh,h,L] flattened
    int F = l*256 + g;
    int j = F / 38400;                    // 8*L
    int r = F - j*38400;
    int i = r / 4800;
    int ll = r - i*4800;
    return (ll << 8) + (i << 5) + j;
  }
}

// ---------- GEMM: C[M,N] = act(A[M,K] @ B[K,N]) ----------
// A: float or bf16(ushort); B: float; C: float or bf16(ushort)
template<typename TA, typename TC, bool RELU>
__global__ __launch_bounds__(256) void gemm64(const TA* __restrict__ A, const float* __restrict__ B,
                                              TC* __restrict__ C, int M, int N, int K){
  __shared__ float As[16][65];   // As[k][m]
  __shared__ float Bs[16][65];   // Bs[k][n]
  const int tid = threadIdx.x;
  const int tx = tid & 15, ty = tid >> 4;
  const int row0 = blockIdx.y << 6, col0 = blockIdx.x << 6;
  const int ar = tid >> 2;            // 0..63
  const int ak = (tid & 3) << 2;      // 0,4,8,12
  const int bk = tid >> 4;            // 0..15
  const int bc = (tid & 15) << 2;     // 0..60
  float acc[4][4] = {};
  for (int k0 = 0; k0 < K; k0 += 16){
    float a0,a1,a2,a3;
    const TA* ap = A + (size_t)(row0 + ar)*K + (k0 + ak);
    if constexpr (std::is_same<TA,float>::value){
      float4 t = *(const float4*)ap; a0=t.x; a1=t.y; a2=t.z; a3=t.w;
    } else {
      ushort4 t = *(const ushort4*)ap; a0=bf2f(t.x); a1=bf2f(t.y); a2=bf2f(t.z); a3=bf2f(t.w);
    }
    As[ak+0][ar]=a0; As[ak+1][ar]=a1; As[ak+2][ar]=a2; As[ak+3][ar]=a3;
    float4 bv = *(const float4*)(B + (size_t)(k0 + bk)*N + (col0 + bc));
    Bs[bk][bc+0]=bv.x; Bs[bk][bc+1]=bv.y; Bs[bk][bc+2]=bv.z; Bs[bk][bc+3]=bv.w;
    __syncthreads();
    #pragma unroll
    for (int kk = 0; kk < 16; kk++){
      float av[4], bvv[4];
      #pragma unroll
      for (int i = 0; i < 4; i++) av[i]  = As[kk][(ty<<2)+i];
      #pragma unroll
      for (int j = 0; j < 4; j++) bvv[j] = Bs[kk][(tx<<2)+j];
      #pragma unroll
      for (int i = 0; i < 4; i++)
        #pragma unroll
        for (int j = 0; j < 4; j++)
          acc[i][j] += av[i]*bvv[j];
    }
    __syncthreads();
  }
  #pragma unroll
  for (int i = 0; i < 4; i++){
    size_t crow = (size_t)(row0 + (ty<<2) + i)*N + col0 + (tx<<2);
    #pragma unroll
    for (int j = 0; j < 4; j++){
      float v = acc[i][j];
      if constexpr (RELU) v = v > 0.f ? v : 0.f;
      if constexpr (std::is_same<TC,float>::value) C[crow + j] = v;
      else                                         C[crow + j] = f2bf(v);
    }
  }
}

// ---------- attention phase A: KVraw[n][h][32][32], Ksum[n][h][32] ----------
template<int MODE>
__global__ __launch_bounds__(256) void attn_stats(const unsigned short* __restrict__ kq,
                                                  const unsigned short* __restrict__ vq,
                                                  float* __restrict__ KV, float* __restrict__ Ksum){
  const int chunk = blockIdx.x, h = blockIdx.y, n = blockIdx.z;
  const int t = threadIdx.x;
  const int d = t >> 3;            // 0..31
  const int w4 = (t & 7) << 2;     // 0,4,..,28
  const size_t boff = (size_t)n * PERBATCH;
  __shared__ float kb[8][32], vb[8][32];
  const int lr = t >> 5, lj = t & 31;
  float a0=0.f, a1=0.f, a2=0.f, a3=0.f, ks=0.f;
  const int s0 = chunk * 240;
  for (int s = s0; s < s0 + 240; s += 8){
    int srci = perm_src<MODE>(s + lr, (h << 5) + lj);
    kb[lr][lj] = phi(bf2f(kq[boff + srci]));
    vb[lr][lj] = bf2f(vq[boff + srci]);
    __syncthreads();
    #pragma unroll
    for (int r = 0; r < 8; r++){
      float kd = kb[r][d];
      ks += kd;
      a0 += kd * vb[r][w4+0];
      a1 += kd * vb[r][w4+1];
      a2 += kd * vb[r][w4+2];
      a3 += kd * vb[r][w4+3];
    }
    __syncthreads();
  }
  float* kvp = KV + (size_t)((((n<<3)+h)<<5) + d)*32 + w4;
  atomicAdd(kvp+0, a0);
  atomicAdd(kvp+1, a1);
  atomicAdd(kvp+2, a2);
  atomicAdd(kvp+3, a3);
  if ((t & 7) == 0) atomicAdd(Ksum + (((n<<3)+h)<<5) + d, ks);
}

// ---------- attention phase B: msg[n,l',:] in permuted-row space ----------
template<int MODE>
__global__ __launch_bounds__(256) void attn_apply(const unsigned short* __restrict__ qq,
                                                  const float* __restrict__ KV,
                                                  const float* __restrict__ Ksum,
                                                  unsigned short* __restrict__ msg){
  const int l = blockIdx.x, n = blockIdx.y;
  const int t = threadIdx.x;
  const size_t boff = (size_t)n * PERBATCH;
  __shared__ float Qp[256];
  Qp[t] = phi(bf2f(qq[boff + perm_src<MODE>(l, t)]));
  __syncthreads();
  const int h = t >> 5, w = t & 31;
  const float* ks = Ksum + (((n<<3)+h)<<5);
  const float* kv = KV + (size_t)(((n<<3)+h)<<5)*32 + w;
  float denom = 1e-6f, out = 0.f;
  #pragma unroll
  for (int dd = 0; dd < 32; dd++){
    float qd = Qp[(h<<5)+dd];
    denom += qd * ks[dd];
    out   += qd * kv[dd*32];
  }
  msg[boff + (size_t)l*256 + t] = f2bf(out/denom);
}

// ---------- layernorm ----------
__device__ __forceinline__ float blockSum256(float v){
  #pragma unroll
  for (int o = 32; o > 0; o >>= 1) v += __shfl_down(v, o, 64);
  __shared__ float sb[4];
  const int lane = threadIdx.x & 63, wid = threadIdx.x >> 6;
  __syncthreads();
  if (lane == 0) sb[wid] = v;
  __syncthreads();
  return sb[0]+sb[1]+sb[2]+sb[3];
}

__global__ __launch_bounds__(256) void ln_bf16(const float* __restrict__ X, const float* __restrict__ g,
                                               const float* __restrict__ b, unsigned short* __restrict__ dst,
                                               int stride, int off){
  const int row = blockIdx.x, t = threadIdx.x;
  float x = X[(size_t)row*256 + t];
  float mu = blockSum256(x) * (1.f/256.f);
  float xm = x - mu;
  float var = blockSum256(xm*xm) * (1.f/256.f);
  float y = xm * rsqrtf(var + 1e-5f) * g[t] + b[t];
  dst[(size_t)row*stride + off + t] = f2bf(y);
}

__global__ __launch_bounds__(256) void ln_acc(const float* __restrict__ X, const float* __restrict__ g,
                                              const float* __restrict__ b, float* __restrict__ macc, int add){
  const int row = blockIdx.x, t = threadIdx.x;
  float x = X[(size_t)row*256 + t];
  float mu = blockSum256(x) * (1.f/256.f);
  float xm = x - mu;
  float var = blockSum256(xm*xm) * (1.f/256.f);
  float y = xm * rsqrtf(var + 1e-5f) * g[t] + b[t];
  size_t i = (size_t)row*256 + t;
  macc[i] = add ? (macc[i] + y) : y;
}

// ---------- elementwise ----------
__global__ __launch_bounds__(256) void fill_hcat(const float* __restrict__ x, unsigned short* __restrict__ hcat){
  size_t i = (size_t)blockIdx.x*256 + threadIdx.x;
  hcat[(i >> 8)*512 + (i & 255)] = f2bf(x[i]);
}
// xmid (stored into out, f32) = x + 0.5*macc; also refresh hcat left half (bf16)
__global__ __launch_bounds__(256) void xmid_k(const float* __restrict__ x, const float* __restrict__ macc,
                                              float* __restrict__ xmid, unsigned short* __restrict__ hcat){
  size_t i = (size_t)blockIdx.x*256 + threadIdx.x;
  float v = x[i] + 0.5f*macc[i];
  xmid[i] = v;
  hcat[(i >> 8)*512 + (i & 255)] = f2bf(v);
}
// out = out + 0.5*macc (in place; out currently holds xmid, f32)
__global__ __launch_bounds__(256) void final_k(float* __restrict__ out, const float* __restrict__ macc){
  size_t i = (size_t)blockIdx.x*256 + threadIdx.x;
  out[i] = out[i] + 0.5f*macc[i];
}
__global__ __launch_bounds__(256) void zero_k(float* __restrict__ p, int n){
  int i = blockIdx.x*256 + threadIdx.x;
  if (i < n) p[i] = 0.f;
}

// ---------- orchestration ----------
extern "C" void kernel_launch(void* const* d_in, const int* in_sizes, int n_in,
                              void* d_out, int out_size, void* d_ws, size_t ws_size,
                              hipStream_t stream){
  // Inputs are float32 (per reference setup_inputs); output float32.
  const float* x   = (const float*)d_in[0];
  const float* src = (const float*)d_in[1];
  const float* Wq  = (const float*)d_in[2];
  const float* Wk  = (const float*)d_in[3];
  const float* Wv  = (const float*)d_in[4];
  const float* Wm  = (const float*)d_in[5];
  const float* W1  = (const float*)d_in[6];
  const float* W2  = (const float*)d_in[7];
  const float* g1  = (const float*)d_in[8];
  const float* b1  = (const float*)d_in[9];
  const float* g2  = (const float*)d_in[10];
  const float* b2  = (const float*)d_in[11];
  float* out = (float*)d_out;          // also used as xmid scratch (fully rewritten)

  // ---- workspace layout (≈178 MB total) ----
  char* ws = (char*)d_ws;
  size_t off = 0;
  auto alloc = [&](size_t bytes) -> void* {
    void* p = ws + off;
    off += (bytes + 255) & ~(size_t)255;
    return p;
  };
  unsigned short* qB    = (unsigned short*)alloc((size_t)MROWS*256*2);  // persists
  unsigned short* kB    = (unsigned short*)alloc((size_t)MROWS*256*2);  // dead after stats -> msg/hid
  unsigned short* vB    = (unsigned short*)alloc((size_t)MROWS*256*2);  // dead after stats -> hid(2nd half)
  unsigned short* hcatB = (unsigned short*)alloc((size_t)MROWS*512*2);
  float* t1   = (float*)alloc((size_t)MROWS*256*4);
  float* macc = (float*)alloc((size_t)MROWS*256*4);
  float* KV4  = (float*)alloc((size_t)4*KVSET*4);   // per-mode: 65536 KV + 2048 Ksum
  (void)ws_size; (void)in_sizes; (void)n_in; (void)out_size;

  unsigned short* msgB = kB;   // alias: msg dead before hid written
  unsigned short* hidB = kB;   // hid spans kB+vB (contiguous, 38400*512 bf16)
  float* xmid = out;

  const dim3 blk(256);

  // projections (f32 in, bf16 out)
  gemm64<float, unsigned short, false><<<dim3(4,600), blk, 0, stream>>>(x,   Wq, qB, MROWS, 256, 256);
  gemm64<float, unsigned short, false><<<dim3(4,600), blk, 0, stream>>>(src, Wk, kB, MROWS, 256, 256);
  gemm64<float, unsigned short, false><<<dim3(4,600), blk, 0, stream>>>(src, Wv, vB, MROWS, 256, 256);

  // zero all 4 KV/Ksum sets, then all-mode stats upfront (k/v die after this)
  zero_k<<<dim3(1056), blk, 0, stream>>>(KV4, 4*KVSET);
  attn_stats<0><<<dim3(20,8,8), blk, 0, stream>>>(kB, vB, KV4 + 0*KVSET, KV4 + 0*KVSET + 65536);
  attn_stats<1><<<dim3(20,8,8), blk, 0, stream>>>(kB, vB, KV4 + 1*KVSET, KV4 + 1*KVSET + 65536);
  attn_stats<2><<<dim3(20,8,8), blk, 0, stream>>>(kB, vB, KV4 + 2*KVSET, KV4 + 2*KVSET + 65536);
  attn_stats<3><<<dim3(20,8,8), blk, 0, stream>>>(kB, vB, KV4 + 3*KVSET, KV4 + 3*KVSET + 65536);

  // hcat left half = x (bf16)
  fill_hcat<<<dim3(MROWS), blk, 0, stream>>>(x, hcatB);

  auto run_block = [&](int mode, int add){
    const float* KV   = KV4 + (size_t)mode*KVSET;
    const float* Ksum = KV + 65536;
    switch (mode){
      case 0: attn_apply<0><<<dim3(L_SEQ,BS), blk, 0, stream>>>(qB, KV, Ksum, msgB); break;
      case 1: attn_apply<1><<<dim3(L_SEQ,BS), blk, 0, stream>>>(qB, KV, Ksum, msgB); break;
      case 2: attn_apply<2><<<dim3(L_SEQ,BS), blk, 0, stream>>>(qB, KV, Ksum, msgB); break;
      default: attn_apply<3><<<dim3(L_SEQ,BS), blk, 0, stream>>>(qB, KV, Ksum, msgB); break;
    }
    // msg @ Wm -> t1 (f32)   [M=38400, N=256, K=256]
    gemm64<unsigned short, float, false><<<dim3(4,600), blk, 0, stream>>>(msgB, Wm, t1, MROWS, 256, 256);
    // LN1 -> hcat right half (bf16)
    ln_bf16<<<dim3(MROWS), blk, 0, stream>>>(t1, g1, b1, hcatB, 512, 256);
    // hidden = relu(hcat @ W1) (bf16)  [M=38400, N=512, K=512]
    gemm64<unsigned short, unsigned short, true><<<dim3(8,600), blk, 0, stream>>>(hcatB, W1, hidB, MROWS, 512, 512);
    // t1 = hidden @ W2 (f32)  [M=38400, N=256, K=512]  (fixed M/N/K order)
    gemm64<unsigned short, float, false><<<dim3(4,600), blk, 0, stream>>>(hidB, W2, t1, MROWS, 256, 512);
    // LN2 -> macc (set or add)
    ln_acc<<<dim3(MROWS), blk, 0, stream>>>(t1, g2, b2, macc, add);
  };

  run_block(0, 0);   // m   (identity)
  run_block(1, 1);   // m3  (p13)
  // x_mid = x + 0.5*(m+m3) -> out (f32); hcat left half = x_mid (bf16)
  xmid_k<<<dim3(MROWS), blk, 0, stream>>>(x, macc, xmid, hcatB);
  run_block(2, 0);   // m1  (p21)
  run_block(3, 1);   // m2  (p32)
  // out = x_mid + 0.5*(m1+m2)  (in place)
  final_k<<<dim3(MROWS), blk, 0, stream>>>(out, macc);
}

// Round 5
// 1578.678 us; speedup vs baseline: 2.6515x; 2.6515x over previous
//
#include <hip/hip_runtime.h>
#include <type_traits>
#include <cstdint>
#include <cstddef>

#define L_SEQ 4800
#define DMODEL 256
#define BS 8
#define MROWS (BS*L_SEQ)          // 38400
#define PERBATCH (L_SEQ*DMODEL)   // 1228800
#define KVSET 67584               // 65536 KV + 2048 Ksum floats per mode

typedef __attribute__((ext_vector_type(8))) short bfrag8;
typedef __attribute__((ext_vector_type(4))) float floatx4;

// ---------- helpers ----------
__device__ __forceinline__ float bf2f(unsigned short u){
  union { unsigned int i; float f; } x; x.i = ((unsigned int)u) << 16; return x.f;
}
__device__ __forceinline__ unsigned short f2bf(float f){
  union { float f; unsigned int i; } x; x.f = f;
  x.i += 0x7fff + ((x.i >> 16) & 1);   // RNE
  return (unsigned short)(x.i >> 16);
}
// phi(x) = elu(x) + 1
__device__ __forceinline__ float phi(float x){
  return x > 0.f ? x + 1.f : __expf(x);
}

// permuted (l,g) -> original flat index within one batch's [4800*256] buffer
template<int MODE>
__device__ __forceinline__ int perm_src(int l, int g){
  if constexpr (MODE == 0){
    return l*256 + g;
  } else if constexpr (MODE == 1){        // p13
    return l*256 + ((g & 7) << 5) + (g >> 3);
  } else if constexpr (MODE == 2){        // p21
    int F = l*256 + g;
    int i = F / 153600;                   // L*32
    int r = F - i*153600;
    return ((r >> 5) << 8) + (i << 5) + (r & 31);
  } else {                                // p32
    int F = l*256 + g;
    int j = F / 38400;                    // 8*L
    int r = F - j*38400;
    int i = r / 4800;
    int ll = r - i*4800;
    return (ll << 8) + (i << 5) + j;
  }
}

// ---------- MFMA GEMM: C[M,N] = act(A[M,K] @ Bt[N,K]^T) ----------
// A, Bt bf16 row-major; C float or bf16. 128x128 tile, BK=32, 4 waves.
template<typename TC, bool RELU>
__global__ __launch_bounds__(256) void gemm_mfma(const unsigned short* __restrict__ A,
                                                 const unsigned short* __restrict__ Bt,
                                                 TC* __restrict__ C, int M, int N, int K){
  __shared__ unsigned short Al[128*32];   // [row][k] contiguous
  __shared__ unsigned short Bl[128*32];   // [col][k] contiguous
  const int tid  = threadIdx.x;
  const int lane = tid & 63;
  const int wave = tid >> 6;
  const int row0 = blockIdx.y << 7;
  const int col0 = blockIdx.x << 7;
  const int wr0  = (wave & 1) << 6;    // wave row offset within tile
  const int wc0  = (wave >> 1) << 6;   // wave col offset within tile

  floatx4 acc[4][4] = {};

  // staging: load unit i covers LDS bytes [i*16, i*16+16); i = tid + 256*j
  const int i0 = tid, i1 = tid + 256;
  const int r0 = i0 >> 2, s0 = i0 & 3;
  const int r1 = i1 >> 2, s1 = i1 & 3;
  const int m = lane & 15, q = lane >> 4;

  for (int k0 = 0; k0 < K; k0 += 32){
    const unsigned short* ga0 = A  + (size_t)(row0 + r0)*K + k0 + s0*8;
    const unsigned short* ga1 = A  + (size_t)(row0 + r1)*K + k0 + s1*8;
    const unsigned short* gb0 = Bt + (size_t)(col0 + r0)*K + k0 + s0*8;
    const unsigned short* gb1 = Bt + (size_t)(col0 + r1)*K + k0 + s1*8;
    __builtin_amdgcn_global_load_lds((const __attribute__((address_space(1))) unsigned int*)ga0,
        (__attribute__((address_space(3))) unsigned int*)(Al + (size_t)i0*8), 16, 0, 0);
    __builtin_amdgcn_global_load_lds((const __attribute__((address_space(1))) unsigned int*)ga1,
        (__attribute__((address_space(3))) unsigned int*)(Al + (size_t)i1*8), 16, 0, 0);
    __builtin_amdgcn_global_load_lds((const __attribute__((address_space(1))) unsigned int*)gb0,
        (__attribute__((address_space(3))) unsigned int*)(Bl + (size_t)i0*8), 16, 0, 0);
    __builtin_amdgcn_global_load_lds((const __attribute__((address_space(1))) unsigned int*)gb1,
        (__attribute__((address_space(3))) unsigned int*)(Bl + (size_t)i1*8), 16, 0, 0);
    __builtin_amdgcn_s_waitcnt(0);
    __syncthreads();

    bfrag8 af[4], bf[4];
    #pragma unroll
    for (int t = 0; t < 4; t++){
      af[t] = *(const bfrag8*)(Al + (size_t)(wr0 + t*16 + m)*32 + q*8);
      bf[t] = *(const bfrag8*)(Bl + (size_t)(wc0 + t*16 + m)*32 + q*8);
    }
    #pragma unroll
    for (int mt = 0; mt < 4; mt++)
      #pragma unroll
      for (int nt = 0; nt < 4; nt++)
        acc[mt][nt] = __builtin_amdgcn_mfma_f32_16x16x32_bf16(af[mt], bf[nt], acc[mt][nt], 0, 0, 0);
    __syncthreads();
  }

  // epilogue: C/D layout col=lane&15, row=(lane>>4)*4+i
  #pragma unroll
  for (int mt = 0; mt < 4; mt++){
    #pragma unroll
    for (int nt = 0; nt < 4; nt++){
      const int col  = col0 + wc0 + nt*16 + m;
      const int rowb = row0 + wr0 + mt*16 + q*4;
      #pragma unroll
      for (int i = 0; i < 4; i++){
        float v = acc[mt][nt][i];
        if (RELU) v = v > 0.f ? v : 0.f;
        if constexpr (std::is_same<TC,float>::value) C[(size_t)(rowb+i)*N + col] = v;
        else                                         C[(size_t)(rowb+i)*N + col] = f2bf(v);
      }
    }
  }
}

// ---------- one-time converts ----------
// Wt[n*K+k] = bf16(W[k*N+n]); K pow2 (kshift)
__global__ __launch_bounds__(256) void wconv(const float* __restrict__ W, unsigned short* __restrict__ Wt,
                                             int kshift, int N){
  int idx = blockIdx.x*256 + threadIdx.x;
  int kk = idx & ((1 << kshift) - 1);
  int nn = idx >> kshift;
  Wt[idx] = f2bf(W[(size_t)kk*N + nn]);
}
// vectorized f32 -> bf16 (n4 = n/4 threads)
__global__ __launch_bounds__(256) void conv_bf16(const float* __restrict__ in, unsigned short* __restrict__ out){
  int i = blockIdx.x*256 + threadIdx.x;
  float4 v = ((const float4*)in)[i];
  ushort4 o; o.x = f2bf(v.x); o.y = f2bf(v.y); o.z = f2bf(v.z); o.w = f2bf(v.w);
  ((ushort4*)out)[i] = o;
}

// ---------- attention phase A: KVraw[n][h][32][32], Ksum[n][h][32] ----------
template<int MODE>
__global__ __launch_bounds__(256) void attn_stats(const unsigned short* __restrict__ kq,
                                                  const unsigned short* __restrict__ vq,
                                                  float* __restrict__ KV, float* __restrict__ Ksum){
  const int chunk = blockIdx.x, h = blockIdx.y, n = blockIdx.z;
  const int t = threadIdx.x;
  const int d = t >> 3;            // 0..31
  const int w4 = (t & 7) << 2;     // 0,4,..,28
  const size_t boff = (size_t)n * PERBATCH;
  __shared__ float kb[8][32], vb[8][32];
  const int lr = t >> 5, lj = t & 31;
  float a0=0.f, a1=0.f, a2=0.f, a3=0.f, ks=0.f;
  const int s0 = chunk * 240;
  for (int s = s0; s < s0 + 240; s += 8){
    int srci = perm_src<MODE>(s + lr, (h << 5) + lj);
    kb[lr][lj] = phi(bf2f(kq[boff + srci]));
    vb[lr][lj] = bf2f(vq[boff + srci]);
    __syncthreads();
    #pragma unroll
    for (int r = 0; r < 8; r++){
      float kd = kb[r][d];
      ks += kd;
      a0 += kd * vb[r][w4+0];
      a1 += kd * vb[r][w4+1];
      a2 += kd * vb[r][w4+2];
      a3 += kd * vb[r][w4+3];
    }
    __syncthreads();
  }
  float* kvp = KV + (size_t)((((n<<3)+h)<<5) + d)*32 + w4;
  atomicAdd(kvp+0, a0);
  atomicAdd(kvp+1, a1);
  atomicAdd(kvp+2, a2);
  atomicAdd(kvp+3, a3);
  if ((t & 7) == 0) atomicAdd(Ksum + (((n<<3)+h)<<5) + d, ks);
}

// ---------- attention phase B: msg[n,l',:] in permuted-row space ----------
template<int MODE>
__global__ __launch_bounds__(256) void attn_apply(const unsigned short* __restrict__ qq,
                                                  const float* __restrict__ KV,
                                                  const float* __restrict__ Ksum,
                                                  unsigned short* __restrict__ msg){
  const int l = blockIdx.x, n = blockIdx.y;
  const int t = threadIdx.x;
  const size_t boff = (size_t)n * PERBATCH;
  __shared__ float Qp[256];
  Qp[t] = phi(bf2f(qq[boff + perm_src<MODE>(l, t)]));
  __syncthreads();
  const int h = t >> 5, w = t & 31;
  const float* ks = Ksum + (((n<<3)+h)<<5);
  const float* kv = KV + (size_t)(((n<<3)+h)<<5)*32 + w;
  float denom = 1e-6f, out = 0.f;
  #pragma unroll
  for (int dd = 0; dd < 32; dd++){
    float qd = Qp[(h<<5)+dd];
    denom += qd * ks[dd];
    out   += qd * kv[dd*32];
  }
  msg[boff + (size_t)l*256 + t] = f2bf(out/denom);
}

// ---------- layernorm ----------
__device__ __forceinline__ float blockSum256(float v){
  #pragma unroll
  for (int o = 32; o > 0; o >>= 1) v += __shfl_down(v, o, 64);
  __shared__ float sb[4];
  const int lane = threadIdx.x & 63, wid = threadIdx.x >> 6;
  __syncthreads();
  if (lane == 0) sb[wid] = v;
  __syncthreads();
  return sb[0]+sb[1]+sb[2]+sb[3];
}

__global__ __launch_bounds__(256) void ln_bf16(const float* __restrict__ X, const float* __restrict__ g,
                                               const float* __restrict__ b, unsigned short* __restrict__ dst,
                                               int stride, int off){
  const int row = blockIdx.x, t = threadIdx.x;
  float x = X[(size_t)row*256 + t];
  float mu = blockSum256(x) * (1.f/256.f);
  float xm = x - mu;
  float var = blockSum256(xm*xm) * (1.f/256.f);
  float y = xm * rsqrtf(var + 1e-5f) * g[t] + b[t];
  dst[(size_t)row*stride + off + t] = f2bf(y);
}

__global__ __launch_bounds__(256) void ln_acc(const float* __restrict__ X, const float* __restrict__ g,
                                              const float* __restrict__ b, float* __restrict__ macc, int add){
  const int row = blockIdx.x, t = threadIdx.x;
  float x = X[(size_t)row*256 + t];
  float mu = blockSum256(x) * (1.f/256.f);
  float xm = x - mu;
  float var = blockSum256(xm*xm) * (1.f/256.f);
  float y = xm * rsqrtf(var + 1e-5f) * g[t] + b[t];
  size_t i = (size_t)row*256 + t;
  macc[i] = add ? (macc[i] + y) : y;
}

// ---------- elementwise ----------
__global__ __launch_bounds__(256) void fill_hcat(const float* __restrict__ x, unsigned short* __restrict__ hcat){
  size_t i = (size_t)blockIdx.x*256 + threadIdx.x;
  hcat[(i >> 8)*512 + (i & 255)] = f2bf(x[i]);
}
__global__ __launch_bounds__(256) void xmid_k(const float* __restrict__ x, const float* __restrict__ macc,
                                              float* __restrict__ xmid, unsigned short* __restrict__ hcat){
  size_t i = (size_t)blockIdx.x*256 + threadIdx.x;
  float v = x[i] + 0.5f*macc[i];
  xmid[i] = v;
  hcat[(i >> 8)*512 + (i & 255)] = f2bf(v);
}
__global__ __launch_bounds__(256) void final_k(float* __restrict__ out, const float* __restrict__ macc){
  size_t i = (size_t)blockIdx.x*256 + threadIdx.x;
  out[i] = out[i] + 0.5f*macc[i];
}
__global__ __launch_bounds__(256) void zero_k(float* __restrict__ p, int n){
  int i = blockIdx.x*256 + threadIdx.x;
  if (i < n) p[i] = 0.f;
}

// ---------- orchestration ----------
extern "C" void kernel_launch(void* const* d_in, const int* in_sizes, int n_in,
                              void* d_out, int out_size, void* d_ws, size_t ws_size,
                              hipStream_t stream){
  const float* x   = (const float*)d_in[0];
  const float* src = (const float*)d_in[1];
  const float* Wq  = (const float*)d_in[2];
  const float* Wk  = (const float*)d_in[3];
  const float* Wv  = (const float*)d_in[4];
  const float* Wm  = (const float*)d_in[5];
  const float* W1  = (const float*)d_in[6];
  const float* W2  = (const float*)d_in[7];
  const float* g1  = (const float*)d_in[8];
  const float* b1  = (const float*)d_in[9];
  const float* g2  = (const float*)d_in[10];
  const float* b2  = (const float*)d_in[11];
  float* out = (float*)d_out;          // also used as xmid scratch (fully rewritten)

  // ---- workspace layout (~179.5 MB) ----
  char* ws = (char*)d_ws;
  size_t off = 0;
  auto alloc = [&](size_t bytes) -> void* {
    void* p = ws + off;
    off += (bytes + 255) & ~(size_t)255;
    return p;
  };
  unsigned short* qB    = (unsigned short*)alloc((size_t)MROWS*256*2);  // persists
  unsigned short* kB    = (unsigned short*)alloc((size_t)MROWS*256*2);  // dead after stats -> msg/hid
  unsigned short* vB    = (unsigned short*)alloc((size_t)MROWS*256*2);  // dead after stats -> hid tail
  unsigned short* hcatB = (unsigned short*)alloc((size_t)MROWS*512*2);
  float* t1   = (float*)alloc((size_t)MROWS*256*4);   // GEMM f32 out; start: aliases srcbf+xbf
  float* macc = (float*)alloc((size_t)MROWS*256*4);
  float* KV4  = (float*)alloc((size_t)4*KVSET*4);
  unsigned short* WqT = (unsigned short*)alloc((size_t)256*256*2);
  unsigned short* WkT = (unsigned short*)alloc((size_t)256*256*2);
  unsigned short* WvT = (unsigned short*)alloc((size_t)256*256*2);
  unsigned short* WmT = (unsigned short*)alloc((size_t)256*256*2);
  unsigned short* W1T = (unsigned short*)alloc((size_t)512*512*2);
  unsigned short* W2T = (unsigned short*)alloc((size_t)256*512*2);
  (void)ws_size; (void)in_sizes; (void)n_in; (void)out_size;

  unsigned short* msgB  = kB;                          // alias
  unsigned short* hidB  = kB;                          // spans kB+vB (contiguous)
  unsigned short* srcbf = (unsigned short*)t1;         // alias (dead before t1 written)
  unsigned short* xbf   = srcbf + (size_t)MROWS*256;
  float* xmid = out;

  const dim3 blk(256);

  // one-time converts: weights (transposed bf16) + activations (bf16)
  wconv<<<dim3(256),  blk, 0, stream>>>(Wq, WqT, 8, 256);
  wconv<<<dim3(256),  blk, 0, stream>>>(Wk, WkT, 8, 256);
  wconv<<<dim3(256),  blk, 0, stream>>>(Wv, WvT, 8, 256);
  wconv<<<dim3(256),  blk, 0, stream>>>(Wm, WmT, 8, 256);
  wconv<<<dim3(1024), blk, 0, stream>>>(W1, W1T, 9, 512);
  wconv<<<dim3(512),  blk, 0, stream>>>(W2, W2T, 9, 256);
  conv_bf16<<<dim3(9600), blk, 0, stream>>>(src, srcbf);
  conv_bf16<<<dim3(9600), blk, 0, stream>>>(x,   xbf);

  // projections (bf16 A/B -> bf16 out), 128x128 tiles
  gemm_mfma<unsigned short, false><<<dim3(2,300), blk, 0, stream>>>(xbf,   WqT, qB, MROWS, 256, 256);
  gemm_mfma<unsigned short, false><<<dim3(2,300), blk, 0, stream>>>(srcbf, WkT, kB, MROWS, 256, 256);
  gemm_mfma<unsigned short, false><<<dim3(2,300), blk, 0, stream>>>(srcbf, WvT, vB, MROWS, 256, 256);

  // zero all 4 KV/Ksum sets, then all-mode stats upfront (k/v die after this)
  zero_k<<<dim3(1056), blk, 0, stream>>>(KV4, 4*KVSET);
  attn_stats<0><<<dim3(20,8,8), blk, 0, stream>>>(kB, vB, KV4 + 0*KVSET, KV4 + 0*KVSET + 65536);
  attn_stats<1><<<dim3(20,8,8), blk, 0, stream>>>(kB, vB, KV4 + 1*KVSET, KV4 + 1*KVSET + 65536);
  attn_stats<2><<<dim3(20,8,8), blk, 0, stream>>>(kB, vB, KV4 + 2*KVSET, KV4 + 2*KVSET + 65536);
  attn_stats<3><<<dim3(20,8,8), blk, 0, stream>>>(kB, vB, KV4 + 3*KVSET, KV4 + 3*KVSET + 65536);

  // hcat left half = x (bf16)
  fill_hcat<<<dim3(MROWS), blk, 0, stream>>>(x, hcatB);

  auto run_block = [&](int mode, int add){
    const float* KV   = KV4 + (size_t)mode*KVSET;
    const float* Ksum = KV + 65536;
    switch (mode){
      case 0: attn_apply<0><<<dim3(L_SEQ,BS), blk, 0, stream>>>(qB, KV, Ksum, msgB); break;
      case 1: attn_apply<1><<<dim3(L_SEQ,BS), blk, 0, stream>>>(qB, KV, Ksum, msgB); break;
      case 2: attn_apply<2><<<dim3(L_SEQ,BS), blk, 0, stream>>>(qB, KV, Ksum, msgB); break;
      default: attn_apply<3><<<dim3(L_SEQ,BS), blk, 0, stream>>>(qB, KV, Ksum, msgB); break;
    }
    // msg @ Wm -> t1 (f32)   [M, N=256, K=256]
    gemm_mfma<float, false><<<dim3(2,300), blk, 0, stream>>>(msgB, WmT, t1, MROWS, 256, 256);
    // LN1 -> hcat right half (bf16)
    ln_bf16<<<dim3(MROWS), blk, 0, stream>>>(t1, g1, b1, hcatB, 512, 256);
    // hidden = relu(hcat @ W1) (bf16)  [M, N=512, K=512]
    gemm_mfma<unsigned short, true><<<dim3(4,300), blk, 0, stream>>>(hcatB, W1T, hidB, MROWS, 512, 512);
    // t1 = hidden @ W2 (f32)  [M, N=256, K=512]
    gemm_mfma<float, false><<<dim3(2,300), blk, 0, stream>>>(hidB, W2T, t1, MROWS, 256, 512);
    // LN2 -> macc (set or add)
    ln_acc<<<dim3(MROWS), blk, 0, stream>>>(t1, g2, b2, macc, add);
  };

  run_block(0, 0);   // m   (identity)
  run_block(1, 1);   // m3  (p13)
  xmid_k<<<dim3(MROWS), blk, 0, stream>>>(x, macc, xmid, hcatB);
  run_block(2, 0);   // m1  (p21)
  run_block(3, 1);   // m2  (p32)
  final_k<<<dim3(MROWS), blk, 0, stream>>>(out, macc);
}

// Round 6
// 1317.901 us; speedup vs baseline: 3.1761x; 1.1979x over previous
//
#include <hip/hip_runtime.h>
#include <type_traits>
#include <cstdint>
#include <cstddef>

#define L_SEQ 4800
#define DMODEL 256
#define BS 8
#define MROWS (BS*L_SEQ)          // 38400
#define PERBATCH (L_SEQ*DMODEL)   // 1228800
#define KVSET 67584               // 65536 KV + 2048 Ksum floats per mode

typedef __attribute__((ext_vector_type(8))) short bfrag8;
typedef __attribute__((ext_vector_type(4))) float floatx4;

// ---------- helpers ----------
__device__ __forceinline__ float bf2f(unsigned short u){
  union { unsigned int i; float f; } x; x.i = ((unsigned int)u) << 16; return x.f;
}
__device__ __forceinline__ unsigned short f2bf(float f){
  union { float f; unsigned int i; } x; x.f = f;
  x.i += 0x7fff + ((x.i >> 16) & 1);   // RNE
  return (unsigned short)(x.i >> 16);
}
__device__ __forceinline__ float phi(float x){
  return x > 0.f ? x + 1.f : __expf(x);
}

// ---------- MFMA GEMM: C[M,N] = act(A[M,K] @ Bt[N,K]^T) ----------
template<typename TC, bool RELU>
__global__ __launch_bounds__(256) void gemm_mfma(const unsigned short* __restrict__ A,
                                                 const unsigned short* __restrict__ Bt,
                                                 TC* __restrict__ C, int M, int N, int K){
  __shared__ unsigned short Al[128*32];   // [row][k]
  __shared__ unsigned short Bl[128*32];   // [col][k]
  const int tid  = threadIdx.x;
  const int lane = tid & 63;
  const int wave = tid >> 6;
  const int row0 = blockIdx.y << 7;
  const int col0 = blockIdx.x << 7;
  const int wr0  = (wave & 1) << 6;
  const int wc0  = (wave >> 1) << 6;

  floatx4 acc[4][4] = {};

  const int i0 = tid, i1 = tid + 256;
  const int r0 = i0 >> 2, s0 = i0 & 3;
  const int r1 = i1 >> 2, s1 = i1 & 3;
  const int m = lane & 15, q = lane >> 4;

  for (int k0 = 0; k0 < K; k0 += 32){
    const unsigned short* ga0 = A  + (size_t)(row0 + r0)*K + k0 + s0*8;
    const unsigned short* ga1 = A  + (size_t)(row0 + r1)*K + k0 + s1*8;
    const unsigned short* gb0 = Bt + (size_t)(col0 + r0)*K + k0 + s0*8;
    const unsigned short* gb1 = Bt + (size_t)(col0 + r1)*K + k0 + s1*8;
    __builtin_amdgcn_global_load_lds((const __attribute__((address_space(1))) unsigned int*)ga0,
        (__attribute__((address_space(3))) unsigned int*)(Al + (size_t)i0*8), 16, 0, 0);
    __builtin_amdgcn_global_load_lds((const __attribute__((address_space(1))) unsigned int*)ga1,
        (__attribute__((address_space(3))) unsigned int*)(Al + (size_t)i1*8), 16, 0, 0);
    __builtin_amdgcn_global_load_lds((const __attribute__((address_space(1))) unsigned int*)gb0,
        (__attribute__((address_space(3))) unsigned int*)(Bl + (size_t)i0*8), 16, 0, 0);
    __builtin_amdgcn_global_load_lds((const __attribute__((address_space(1))) unsigned int*)gb1,
        (__attribute__((address_space(3))) unsigned int*)(Bl + (size_t)i1*8), 16, 0, 0);
    __builtin_amdgcn_s_waitcnt(0);
    __syncthreads();

    bfrag8 af[4], bf[4];
    #pragma unroll
    for (int t = 0; t < 4; t++){
      af[t] = *(const bfrag8*)(Al + (size_t)(wr0 + t*16 + m)*32 + q*8);
      bf[t] = *(const bfrag8*)(Bl + (size_t)(wc0 + t*16 + m)*32 + q*8);
    }
    #pragma unroll
    for (int mt = 0; mt < 4; mt++)
      #pragma unroll
      for (int nt = 0; nt < 4; nt++)
        acc[mt][nt] = __builtin_amdgcn_mfma_f32_16x16x32_bf16(af[mt], bf[nt], acc[mt][nt], 0, 0, 0);
    __syncthreads();
  }

  #pragma unroll
  for (int mt = 0; mt < 4; mt++){
    #pragma unroll
    for (int nt = 0; nt < 4; nt++){
      const int col  = col0 + wc0 + nt*16 + m;
      const int rowb = row0 + wr0 + mt*16 + q*4;
      #pragma unroll
      for (int i = 0; i < 4; i++){
        float v = acc[mt][nt][i];
        if (RELU) v = v > 0.f ? v : 0.f;
        if constexpr (std::is_same<TC,float>::value) C[(size_t)(rowb+i)*N + col] = v;
        else                                         C[(size_t)(rowb+i)*N + col] = f2bf(v);
      }
    }
  }
}

// ---------- one-time converts ----------
__global__ __launch_bounds__(256) void wconv(const float* __restrict__ W, unsigned short* __restrict__ Wt,
                                             int kshift, int N){
  int idx = blockIdx.x*256 + threadIdx.x;
  int kk = idx & ((1 << kshift) - 1);
  int nn = idx >> kshift;
  Wt[idx] = f2bf(W[(size_t)kk*N + nn]);
}
__global__ __launch_bounds__(256) void conv_bf16(const float* __restrict__ in, unsigned short* __restrict__ out){
  int i = blockIdx.x*256 + threadIdx.x;
  float4 v = ((const float4*)in)[i];
  ushort4 o; o.x = f2bf(v.x); o.y = f2bf(v.y); o.z = f2bf(v.z); o.w = f2bf(v.w);
  ((ushort4*)out)[i] = o;
}

// ---------- permute materializers (coalesced both sides via LDS) ----------
// p13: per-row shuffle dst[r*256+g] = src[r*256 + (g&7)*32 + (g>>3)]; 4 rows/block
__global__ __launch_bounds__(256) void permute1(const unsigned short* __restrict__ sA, unsigned short* __restrict__ dA,
                                                const unsigned short* __restrict__ sB, unsigned short* __restrict__ dB){
  const unsigned short* s = blockIdx.z ? sB : sA;
  unsigned short*       d = blockIdx.z ? dB : dA;
  __shared__ unsigned short tile[1024];
  const int t = threadIdx.x;
  const size_t base = (size_t)blockIdx.x * 1024;
  #pragma unroll
  for (int i = 0; i < 4; i++) tile[i*256 + t] = s[base + i*256 + t];
  __syncthreads();
  const int pg = ((t & 7) << 5) + (t >> 3);
  #pragma unroll
  for (int i = 0; i < 4; i++) d[base + i*256 + t] = tile[i*256 + pg];
}

// p21: dst[i*153600 + rr*32 + c] = src[rr*256 + i*32 + c]  (per batch); 64 rows/block
__global__ __launch_bounds__(256) void permute2(const unsigned short* __restrict__ sA, unsigned short* __restrict__ dA,
                                                const unsigned short* __restrict__ sB, unsigned short* __restrict__ dB){
  const unsigned short* s = blockIdx.z ? sB : sA;
  unsigned short*       d = blockIdx.z ? dB : dA;
  __shared__ unsigned short tile[64*256];
  const int t = threadIdx.x;
  const int rr0 = blockIdx.x * 64;
  const size_t boff = (size_t)blockIdx.y * PERBATCH;
  #pragma unroll
  for (int i = 0; i < 16; i++){
    int u = i*256 + t;                 // ushort4 unit of the 64x256 tile
    *(ushort4*)&tile[u*4] = *(const ushort4*)&s[boff + (size_t)rr0*256 + (size_t)u*4];
  }
  __syncthreads();
  #pragma unroll
  for (int i = 0; i < 8; i++){
    #pragma unroll
    for (int w = 0; w < 2; w++){
      int u = w*256 + t;               // ushort4 unit of the 2048-elem output chunk
      int rr = u >> 3, c4 = (u & 7) << 2;
      ushort4 v = *(const ushort4*)&tile[rr*256 + i*32 + c4];
      *(ushort4*)&d[boff + (size_t)i*153600 + (size_t)rr0*32 + (size_t)u*4] = v;
    }
  }
}

// p32: dst[((c&31)*8 + (c>>5))*4800 + ll] = src[ll*256 + c]  (per batch); 64 ll-rows/block
__global__ __launch_bounds__(256) void permute3(const unsigned short* __restrict__ sA, unsigned short* __restrict__ dA,
                                                const unsigned short* __restrict__ sB, unsigned short* __restrict__ dB){
  const unsigned short* s = blockIdx.z ? sB : sA;
  unsigned short*       d = blockIdx.z ? dB : dA;
  __shared__ unsigned short tile[64*258];     // +2 pad: column reads 2-way (free)
  const int t = threadIdx.x;
  const int ll0 = blockIdx.x * 64;
  const size_t boff = (size_t)blockIdx.y * PERBATCH;
  #pragma unroll
  for (int i = 0; i < 32; i++){
    int u = i*256 + t;                 // ushort2 unit
    int row = u >> 7, col = (u & 127) << 1;
    *(ushort2*)&tile[row*258 + col] = *(const ushort2*)&s[boff + (size_t)(ll0+row)*256 + col];
  }
  __syncthreads();
  const int cw = t >> 6;               // 0..3
  const int ll = t & 63;
  #pragma unroll
  for (int cc = 0; cc < 256; cc += 4){
    int c = cc + cw;
    int sigma = ((c & 31) << 3) + (c >> 5);
    d[boff + (size_t)sigma*4800 + ll0 + ll] = tile[ll*258 + c];
  }
}

// ---------- attention phase A (contiguous): KV[n][h][32][32], Ksum[n][h][32] ----------
__global__ __launch_bounds__(256) void attn_stats(const unsigned short* __restrict__ kq,
                                                  const unsigned short* __restrict__ vq,
                                                  float* __restrict__ KV, float* __restrict__ Ksum){
  const int chunk = blockIdx.x, h = blockIdx.y, n = blockIdx.z;
  const int t = threadIdx.x;
  const int d = t >> 3;            // 0..31
  const int w4 = (t & 7) << 2;     // 0,4,..,28
  const size_t boff = (size_t)n * PERBATCH;
  __shared__ float kb[8][32], vb[8][32];
  const int lr = t >> 5, lj = t & 31;
  float a0=0.f, a1=0.f, a2=0.f, a3=0.f, ks=0.f;
  const int s0 = chunk * 240;
  for (int s = s0; s < s0 + 240; s += 8){
    int srci = (s + lr)*256 + (h << 5) + lj;
    kb[lr][lj] = phi(bf2f(kq[boff + srci]));
    vb[lr][lj] = bf2f(vq[boff + srci]);
    __syncthreads();
    #pragma unroll
    for (int r = 0; r < 8; r++){
      float kd = kb[r][d];
      ks += kd;
      a0 += kd * vb[r][w4+0];
      a1 += kd * vb[r][w4+1];
      a2 += kd * vb[r][w4+2];
      a3 += kd * vb[r][w4+3];
    }
    __syncthreads();
  }
  float* kvp = KV + (size_t)((((n<<3)+h)<<5) + d)*32 + w4;
  atomicAdd(kvp+0, a0);
  atomicAdd(kvp+1, a1);
  atomicAdd(kvp+2, a2);
  atomicAdd(kvp+3, a3);
  if ((t & 7) == 0) atomicAdd(Ksum + (((n<<3)+h)<<5) + d, ks);
}

// ---------- attention phase B (contiguous q): msg[n,l,:] ----------
__global__ __launch_bounds__(256) void attn_apply(const unsigned short* __restrict__ qq,
                                                  const float* __restrict__ KV,
                                                  const float* __restrict__ Ksum,
                                                  unsigned short* __restrict__ msg){
  const int l = blockIdx.x, n = blockIdx.y;
  const int t = threadIdx.x;
  const size_t boff = (size_t)n * PERBATCH;
  __shared__ float Qp[256];
  Qp[t] = phi(bf2f(qq[boff + (size_t)l*256 + t]));
  __syncthreads();
  const int h = t >> 5, w = t & 31;
  const float* ks = Ksum + (((n<<3)+h)<<5);
  const float* kv = KV + (size_t)(((n<<3)+h)<<5)*32 + w;
  float denom = 1e-6f, out = 0.f;
  #pragma unroll
  for (int dd = 0; dd < 32; dd++){
    float qd = Qp[(h<<5)+dd];
    denom += qd * ks[dd];
    out   += qd * kv[dd*32];
  }
  msg[boff + (size_t)l*256 + t] = f2bf(out/denom);
}

// ---------- layernorm ----------
__device__ __forceinline__ float blockSum256(float v){
  #pragma unroll
  for (int o = 32; o > 0; o >>= 1) v += __shfl_down(v, o, 64);
  __shared__ float sb[4];
  const int lane = threadIdx.x & 63, wid = threadIdx.x >> 6;
  __syncthreads();
  if (lane == 0) sb[wid] = v;
  __syncthreads();
  return sb[0]+sb[1]+sb[2]+sb[3];
}

__global__ __launch_bounds__(256) void ln_bf16(const float* __restrict__ X, const float* __restrict__ g,
                                               const float* __restrict__ b, unsigned short* __restrict__ dst,
                                               int stride, int off){
  const int row = blockIdx.x, t = threadIdx.x;
  float x = X[(size_t)row*256 + t];
  float mu = blockSum256(x) * (1.f/256.f);
  float xm = x - mu;
  float var = blockSum256(xm*xm) * (1.f/256.f);
  float y = xm * rsqrtf(var + 1e-5f) * g[t] + b[t];
  dst[(size_t)row*stride + off + t] = f2bf(y);
}

__global__ __launch_bounds__(256) void ln_acc(const float* __restrict__ X, const float* __restrict__ g,
                                              const float* __restrict__ b, float* __restrict__ macc, int add){
  const int row = blockIdx.x, t = threadIdx.x;
  float x = X[(size_t)row*256 + t];
  float mu = blockSum256(x) * (1.f/256.f);
  float xm = x - mu;
  float var = blockSum256(xm*xm) * (1.f/256.f);
  float y = xm * rsqrtf(var + 1e-5f) * g[t] + b[t];
  size_t i = (size_t)row*256 + t;
  macc[i] = add ? (macc[i] + y) : y;
}

// ---------- elementwise ----------
__global__ __launch_bounds__(256) void fill_hcat(const float* __restrict__ x, unsigned short* __restrict__ hcat){
  size_t i = (size_t)blockIdx.x*256 + threadIdx.x;
  hcat[(i >> 8)*512 + (i & 255)] = f2bf(x[i]);
}
__global__ __launch_bounds__(256) void xmid_k(const float* __restrict__ x, const float* __restrict__ macc,
                                              float* __restrict__ xmid, unsigned short* __restrict__ hcat){
  size_t i = (size_t)blockIdx.x*256 + threadIdx.x;
  float v = x[i] + 0.5f*macc[i];
  xmid[i] = v;
  hcat[(i >> 8)*512 + (i & 255)] = f2bf(v);
}
__global__ __launch_bounds__(256) void final_k(float* __restrict__ out, const float* __restrict__ macc){
  size_t i = (size_t)blockIdx.x*256 + threadIdx.x;
  out[i] = out[i] + 0.5f*macc[i];
}
__global__ __launch_bounds__(256) void zero_k(float* __restrict__ p, int n){
  int i = blockIdx.x*256 + threadIdx.x;
  if (i < n) p[i] = 0.f;
}

// ---------- orchestration ----------
extern "C" void kernel_launch(void* const* d_in, const int* in_sizes, int n_in,
                              void* d_out, int out_size, void* d_ws, size_t ws_size,
                              hipStream_t stream){
  const float* x   = (const float*)d_in[0];
  const float* src = (const float*)d_in[1];
  const float* Wq  = (const float*)d_in[2];
  const float* Wk  = (const float*)d_in[3];
  const float* Wv  = (const float*)d_in[4];
  const float* Wm  = (const float*)d_in[5];
  const float* W1  = (const float*)d_in[6];
  const float* W2  = (const float*)d_in[7];
  const float* g1  = (const float*)d_in[8];
  const float* b1  = (const float*)d_in[9];
  const float* g2  = (const float*)d_in[10];
  const float* b2  = (const float*)d_in[11];
  float* out = (float*)d_out;

  // ---- workspace layout (~179.5 MB) ----
  char* ws = (char*)d_ws;
  size_t off = 0;
  auto alloc = [&](size_t bytes) -> void* {
    void* p = ws + off;
    off += (bytes + 255) & ~(size_t)255;
    return p;
  };
  unsigned short* qB    = (unsigned short*)alloc((size_t)MROWS*256*2);  // persists
  unsigned short* kB    = (unsigned short*)alloc((size_t)MROWS*256*2);  // dead after stats -> msg/hid
  unsigned short* vB    = (unsigned short*)alloc((size_t)MROWS*256*2);  // dead after stats -> hid tail
  unsigned short* hcatB = (unsigned short*)alloc((size_t)MROWS*512*2);
  float* t1   = (float*)alloc((size_t)MROWS*256*4);   // aliases: srcbf+xbf early; qP per block
  float* macc = (float*)alloc((size_t)MROWS*256*4);   // aliases: kP+vP during stats
  float* KV4  = (float*)alloc((size_t)4*KVSET*4);
  unsigned short* WqT = (unsigned short*)alloc((size_t)256*256*2);
  unsigned short* WkT = (unsigned short*)alloc((size_t)256*256*2);
  unsigned short* WvT = (unsigned short*)alloc((size_t)256*256*2);
  unsigned short* WmT = (unsigned short*)alloc((size_t)256*256*2);
  unsigned short* W1T = (unsigned short*)alloc((size_t)512*512*2);
  unsigned short* W2T = (unsigned short*)alloc((size_t)256*512*2);
  (void)ws_size; (void)in_sizes; (void)n_in; (void)out_size;

  unsigned short* msgB  = kB;                          // alias (dead k)
  unsigned short* hidB  = kB;                          // spans kB+vB
  unsigned short* srcbf = (unsigned short*)t1;         // alias (dead before t1 written)
  unsigned short* xbf   = srcbf + (size_t)MROWS*256;
  unsigned short* qP    = (unsigned short*)t1;         // per-block permuted q (dead before t1 written)
  unsigned short* kP    = (unsigned short*)macc;       // permuted k/v during stats (dead before macc)
  unsigned short* vP    = kP + (size_t)MROWS*256;
  float* xmid = out;

  const dim3 blk(256);

  // one-time converts
  wconv<<<dim3(256),  blk, 0, stream>>>(Wq, WqT, 8, 256);
  wconv<<<dim3(256),  blk, 0, stream>>>(Wk, WkT, 8, 256);
  wconv<<<dim3(256),  blk, 0, stream>>>(Wv, WvT, 8, 256);
  wconv<<<dim3(256),  blk, 0, stream>>>(Wm, WmT, 8, 256);
  wconv<<<dim3(1024), blk, 0, stream>>>(W1, W1T, 9, 512);
  wconv<<<dim3(512),  blk, 0, stream>>>(W2, W2T, 9, 256);
  conv_bf16<<<dim3(9600), blk, 0, stream>>>(src, srcbf);
  conv_bf16<<<dim3(9600), blk, 0, stream>>>(x,   xbf);

  // projections
  gemm_mfma<unsigned short, false><<<dim3(2,300), blk, 0, stream>>>(xbf,   WqT, qB, MROWS, 256, 256);
  gemm_mfma<unsigned short, false><<<dim3(2,300), blk, 0, stream>>>(srcbf, WkT, kB, MROWS, 256, 256);
  gemm_mfma<unsigned short, false><<<dim3(2,300), blk, 0, stream>>>(srcbf, WvT, vB, MROWS, 256, 256);

  // all-mode stats upfront; permuted k/v materialized per mode into kP/vP (macc space)
  zero_k<<<dim3(1056), blk, 0, stream>>>(KV4, 4*KVSET);
  attn_stats<<<dim3(20,8,8), blk, 0, stream>>>(kB, vB, KV4 + 0*KVSET, KV4 + 0*KVSET + 65536);
  permute1<<<dim3(9600,1,2), blk, 0, stream>>>(kB, kP, vB, vP);
  attn_stats<<<dim3(20,8,8), blk, 0, stream>>>(kP, vP, KV4 + 1*KVSET, KV4 + 1*KVSET + 65536);
  permute2<<<dim3(75,8,2),  blk, 0, stream>>>(kB, kP, vB, vP);
  attn_stats<<<dim3(20,8,8), blk, 0, stream>>>(kP, vP, KV4 + 2*KVSET, KV4 + 2*KVSET + 65536);
  permute3<<<dim3(75,8,2),  blk, 0, stream>>>(kB, kP, vB, vP);
  attn_stats<<<dim3(20,8,8), blk, 0, stream>>>(kP, vP, KV4 + 3*KVSET, KV4 + 3*KVSET + 65536);
  // kB/vB dead as k/v from here

  fill_hcat<<<dim3(MROWS), blk, 0, stream>>>(x, hcatB);

  auto run_block = [&](int mode, int add){
    const float* KV   = KV4 + (size_t)mode*KVSET;
    const float* Ksum = KV + 65536;
    const unsigned short* qsrc = qB;
    if (mode == 1){ permute1<<<dim3(9600,1,1), blk, 0, stream>>>(qB, qP, nullptr, nullptr); qsrc = qP; }
    else if (mode == 2){ permute2<<<dim3(75,8,1), blk, 0, stream>>>(qB, qP, nullptr, nullptr); qsrc = qP; }
    else if (mode == 3){ permute3<<<dim3(75,8,1), blk, 0, stream>>>(qB, qP, nullptr, nullptr); qsrc = qP; }
    attn_apply<<<dim3(L_SEQ,BS), blk, 0, stream>>>(qsrc, KV, Ksum, msgB);
    // msg @ Wm -> t1 (f32)   [qP dead from here; t1 overwritten]
    gemm_mfma<float, false><<<dim3(2,300), blk, 0, stream>>>(msgB, WmT, t1, MROWS, 256, 256);
    ln_bf16<<<dim3(MROWS), blk, 0, stream>>>(t1, g1, b1, hcatB, 512, 256);
    gemm_mfma<unsigned short, true><<<dim3(4,300), blk, 0, stream>>>(hcatB, W1T, hidB, MROWS, 512, 512);
    gemm_mfma<float, false><<<dim3(2,300), blk, 0, stream>>>(hidB, W2T, t1, MROWS, 256, 512);
    ln_acc<<<dim3(MROWS), blk, 0, stream>>>(t1, g2, b2, macc, add);
  };

  run_block(0, 0);   // m   (identity)
  run_block(1, 1);   // m3  (p13)
  xmid_k<<<dim3(MROWS), blk, 0, stream>>>(x, macc, xmid, hcatB);
  run_block(2, 0);   // m1  (p21)
  run_block(3, 1);   // m2  (p32)
  final_k<<<dim3(MROWS), blk, 0, stream>>>(out, macc);
}

// Round 7
// 1000.624 us; speedup vs baseline: 4.1832x; 1.3171x over previous
//
#include <hip/hip_runtime.h>
#include <type_traits>
#include <cstdint>
#include <cstddef>

#define L_SEQ 4800
#define DMODEL 256
#define BS 8
#define MROWS (BS*L_SEQ)          // 38400
#define PERBATCH (L_SEQ*DMODEL)   // 1228800
#define KVSET 67584               // 65536 KV + 2048 Ksum floats per mode

typedef __attribute__((ext_vector_type(8))) short bfrag8;
typedef __attribute__((ext_vector_type(4))) float floatx4;

// ---------- helpers ----------
__device__ __forceinline__ float bf2f(unsigned short u){
  union { unsigned int i; float f; } x; x.i = ((unsigned int)u) << 16; return x.f;
}
__device__ __forceinline__ unsigned short f2bf(float f){
  union { float f; unsigned int i; } x; x.f = f;
  x.i += 0x7fff + ((x.i >> 16) & 1);   // RNE
  return (unsigned short)(x.i >> 16);
}
__device__ __forceinline__ float phi(float x){
  return x > 0.f ? x + 1.f : __expf(x);
}

// ---------- MFMA GEMM: C[M,N] = act(A[M,K] @ Bt[N,K]^T) ----------
template<typename TC, bool RELU>
__global__ __launch_bounds__(256) void gemm_mfma(const unsigned short* __restrict__ A,
                                                 const unsigned short* __restrict__ Bt,
                                                 TC* __restrict__ C, int M, int N, int K){
  __shared__ unsigned short Al[128*32];   // [row][k]
  __shared__ unsigned short Bl[128*32];   // [col][k]
  const int tid  = threadIdx.x;
  const int lane = tid & 63;
  const int wave = tid >> 6;
  const int row0 = blockIdx.y << 7;
  const int col0 = blockIdx.x << 7;
  const int wr0  = (wave & 1) << 6;
  const int wc0  = (wave >> 1) << 6;

  floatx4 acc[4][4] = {};

  const int i0 = tid, i1 = tid + 256;
  const int r0 = i0 >> 2, s0 = i0 & 3;
  const int r1 = i1 >> 2, s1 = i1 & 3;
  const int m = lane & 15, q = lane >> 4;

  for (int k0 = 0; k0 < K; k0 += 32){
    const unsigned short* ga0 = A  + (size_t)(row0 + r0)*K + k0 + s0*8;
    const unsigned short* ga1 = A  + (size_t)(row0 + r1)*K + k0 + s1*8;
    const unsigned short* gb0 = Bt + (size_t)(col0 + r0)*K + k0 + s0*8;
    const unsigned short* gb1 = Bt + (size_t)(col0 + r1)*K + k0 + s1*8;
    __builtin_amdgcn_global_load_lds((const __attribute__((address_space(1))) unsigned int*)ga0,
        (__attribute__((address_space(3))) unsigned int*)(Al + (size_t)i0*8), 16, 0, 0);
    __builtin_amdgcn_global_load_lds((const __attribute__((address_space(1))) unsigned int*)ga1,
        (__attribute__((address_space(3))) unsigned int*)(Al + (size_t)i1*8), 16, 0, 0);
    __builtin_amdgcn_global_load_lds((const __attribute__((address_space(1))) unsigned int*)gb0,
        (__attribute__((address_space(3))) unsigned int*)(Bl + (size_t)i0*8), 16, 0, 0);
    __builtin_amdgcn_global_load_lds((const __attribute__((address_space(1))) unsigned int*)gb1,
        (__attribute__((address_space(3))) unsigned int*)(Bl + (size_t)i1*8), 16, 0, 0);
    __builtin_amdgcn_s_waitcnt(0);
    __syncthreads();

    bfrag8 af[4], bf[4];
    #pragma unroll
    for (int t = 0; t < 4; t++){
      af[t] = *(const bfrag8*)(Al + (size_t)(wr0 + t*16 + m)*32 + q*8);
      bf[t] = *(const bfrag8*)(Bl + (size_t)(wc0 + t*16 + m)*32 + q*8);
    }
    #pragma unroll
    for (int mt = 0; mt < 4; mt++)
      #pragma unroll
      for (int nt = 0; nt < 4; nt++)
        acc[mt][nt] = __builtin_amdgcn_mfma_f32_16x16x32_bf16(af[mt], bf[nt], acc[mt][nt], 0, 0, 0);
    __syncthreads();
  }

  #pragma unroll
  for (int mt = 0; mt < 4; mt++){
    #pragma unroll
    for (int nt = 0; nt < 4; nt++){
      const int col  = col0 + wc0 + nt*16 + m;
      const int rowb = row0 + wr0 + mt*16 + q*4;
      #pragma unroll
      for (int i = 0; i < 4; i++){
        float v = acc[mt][nt][i];
        if (RELU) v = v > 0.f ? v : 0.f;
        if constexpr (std::is_same<TC,float>::value) C[(size_t)(rowb+i)*N + col] = v;
        else                                         C[(size_t)(rowb+i)*N + col] = f2bf(v);
      }
    }
  }
}

// ---------- one-time converts ----------
__global__ __launch_bounds__(256) void wconv(const float* __restrict__ W, unsigned short* __restrict__ Wt,
                                             int kshift, int N){
  int idx = blockIdx.x*256 + threadIdx.x;
  int kk = idx & ((1 << kshift) - 1);
  int nn = idx >> kshift;
  Wt[idx] = f2bf(W[(size_t)kk*N + nn]);
}
__global__ __launch_bounds__(256) void conv_bf16(const float* __restrict__ in, unsigned short* __restrict__ out){
  int i = blockIdx.x*256 + threadIdx.x;
  float4 v = ((const float4*)in)[i];
  ushort4 o; o.x = f2bf(v.x); o.y = f2bf(v.y); o.z = f2bf(v.z); o.w = f2bf(v.w);
  ((ushort4*)out)[i] = o;
}

// ---------- permute materializers (coalesced both sides via LDS) ----------
__global__ __launch_bounds__(256) void permute1(const unsigned short* __restrict__ sA, unsigned short* __restrict__ dA,
                                                const unsigned short* __restrict__ sB, unsigned short* __restrict__ dB){
  const unsigned short* s = blockIdx.z ? sB : sA;
  unsigned short*       d = blockIdx.z ? dB : dA;
  __shared__ unsigned short tile[1024];
  const int t = threadIdx.x;
  const size_t base = (size_t)blockIdx.x * 1024;
  #pragma unroll
  for (int i = 0; i < 4; i++) tile[i*256 + t] = s[base + i*256 + t];
  __syncthreads();
  const int pg = ((t & 7) << 5) + (t >> 3);
  #pragma unroll
  for (int i = 0; i < 4; i++) d[base + i*256 + t] = tile[i*256 + pg];
}

__global__ __launch_bounds__(256) void permute2(const unsigned short* __restrict__ sA, unsigned short* __restrict__ dA,
                                                const unsigned short* __restrict__ sB, unsigned short* __restrict__ dB){
  const unsigned short* s = blockIdx.z ? sB : sA;
  unsigned short*       d = blockIdx.z ? dB : dA;
  __shared__ unsigned short tile[64*256];
  const int t = threadIdx.x;
  const int rr0 = blockIdx.x * 64;
  const size_t boff = (size_t)blockIdx.y * PERBATCH;
  #pragma unroll
  for (int i = 0; i < 16; i++){
    int u = i*256 + t;
    *(ushort4*)&tile[u*4] = *(const ushort4*)&s[boff + (size_t)rr0*256 + (size_t)u*4];
  }
  __syncthreads();
  #pragma unroll
  for (int i = 0; i < 8; i++){
    #pragma unroll
    for (int w = 0; w < 2; w++){
      int u = w*256 + t;
      int rr = u >> 3, c4 = (u & 7) << 2;
      ushort4 v = *(const ushort4*)&tile[rr*256 + i*32 + c4];
      *(ushort4*)&d[boff + (size_t)i*153600 + (size_t)rr0*32 + (size_t)u*4] = v;
    }
  }
}

__global__ __launch_bounds__(256) void permute3(const unsigned short* __restrict__ sA, unsigned short* __restrict__ dA,
                                                const unsigned short* __restrict__ sB, unsigned short* __restrict__ dB){
  const unsigned short* s = blockIdx.z ? sB : sA;
  unsigned short*       d = blockIdx.z ? dB : dA;
  __shared__ unsigned short tile[64*258];
  const int t = threadIdx.x;
  const int ll0 = blockIdx.x * 64;
  const size_t boff = (size_t)blockIdx.y * PERBATCH;
  #pragma unroll
  for (int i = 0; i < 32; i++){
    int u = i*256 + t;
    int row = u >> 7, col = (u & 127) << 1;
    *(ushort2*)&tile[row*258 + col] = *(const ushort2*)&s[boff + (size_t)(ll0+row)*256 + col];
  }
  __syncthreads();
  const int cw = t >> 6;
  const int ll = t & 63;
  #pragma unroll
  for (int cc = 0; cc < 256; cc += 4){
    int c = cc + cw;
    int sigma = ((c & 31) << 3) + (c >> 5);
    d[boff + (size_t)sigma*4800 + ll0 + ll] = tile[ll*258 + c];
  }
}

// ---------- attention phase A (contiguous) ----------
__global__ __launch_bounds__(256) void attn_stats(const unsigned short* __restrict__ kq,
                                                  const unsigned short* __restrict__ vq,
                                                  float* __restrict__ KV, float* __restrict__ Ksum){
  const int chunk = blockIdx.x, h = blockIdx.y, n = blockIdx.z;
  const int t = threadIdx.x;
  const int d = t >> 3;
  const int w4 = (t & 7) << 2;
  const size_t boff = (size_t)n * PERBATCH;
  __shared__ float kb[8][32], vb[8][32];
  const int lr = t >> 5, lj = t & 31;
  float a0=0.f, a1=0.f, a2=0.f, a3=0.f, ks=0.f;
  const int s0 = chunk * 240;
  for (int s = s0; s < s0 + 240; s += 8){
    int srci = (s + lr)*256 + (h << 5) + lj;
    kb[lr][lj] = phi(bf2f(kq[boff + srci]));
    vb[lr][lj] = bf2f(vq[boff + srci]);
    __syncthreads();
    #pragma unroll
    for (int r = 0; r < 8; r++){
      float kd = kb[r][d];
      ks += kd;
      a0 += kd * vb[r][w4+0];
      a1 += kd * vb[r][w4+1];
      a2 += kd * vb[r][w4+2];
      a3 += kd * vb[r][w4+3];
    }
    __syncthreads();
  }
  float* kvp = KV + (size_t)((((n<<3)+h)<<5) + d)*32 + w4;
  atomicAdd(kvp+0, a0);
  atomicAdd(kvp+1, a1);
  atomicAdd(kvp+2, a2);
  atomicAdd(kvp+3, a3);
  if ((t & 7) == 0) atomicAdd(Ksum + (((n<<3)+h)<<5) + d, ks);
}

// ---------- attention phase B: 16 rows/block, KV cached in LDS ----------
__global__ __launch_bounds__(256) void attn_apply(const unsigned short* __restrict__ qq,
                                                  const float* __restrict__ KV,
                                                  const float* __restrict__ Ksum,
                                                  unsigned short* __restrict__ msg){
  __shared__ float kvs[8192];   // [h][dd][w]
  __shared__ float kss[256];    // [h][dd]
  __shared__ float Qs[4096];    // [r][256], phi-applied
  const int t = threadIdx.x;
  const int n = blockIdx.y;
  const int row0 = blockIdx.x << 4;
  const size_t boff = (size_t)n * PERBATCH;

  #pragma unroll
  for (int i = 0; i < 32; i++) kvs[i*256 + t] = KV[(size_t)n*8192 + i*256 + t];
  kss[t] = Ksum[n*256 + t];
  #pragma unroll
  for (int r = 0; r < 16; r++)
    Qs[r*256 + t] = phi(bf2f(qq[boff + (size_t)(row0 + r)*256 + t]));
  __syncthreads();

  const int h = t >> 5, w = t & 31;
  const float* kvh = kvs + h*1024;
  const float* ksh = kss + h*32;
  float acc[16], den[16];
  #pragma unroll
  for (int r = 0; r < 16; r++){ acc[r] = 0.f; den[r] = 1e-6f; }

  #pragma unroll
  for (int d4 = 0; d4 < 8; d4++){
    const float k0 = kvh[(d4*4+0)*32 + w];
    const float k1 = kvh[(d4*4+1)*32 + w];
    const float k2 = kvh[(d4*4+2)*32 + w];
    const float k3 = kvh[(d4*4+3)*32 + w];
    const float s0 = ksh[d4*4+0], s1 = ksh[d4*4+1], s2 = ksh[d4*4+2], s3 = ksh[d4*4+3];
    #pragma unroll
    for (int r = 0; r < 16; r++){
      float4 qv = *(const float4*)&Qs[r*256 + h*32 + d4*4];
      acc[r] += qv.x*k0 + qv.y*k1 + qv.z*k2 + qv.w*k3;
      den[r] += qv.x*s0 + qv.y*s1 + qv.z*s2 + qv.w*s3;
    }
  }
  #pragma unroll
  for (int r = 0; r < 16; r++)
    msg[boff + (size_t)(row0 + r)*256 + t] = f2bf(acc[r]/den[r]);
}

// ---------- layernorm (wave-per-row, no __syncthreads) ----------
__device__ __forceinline__ float waveSum(float v){
  #pragma unroll
  for (int o = 32; o > 0; o >>= 1) v += __shfl_xor(v, o, 64);
  return v;
}

__global__ __launch_bounds__(256) void ln_bf16(const float* __restrict__ X, const float* __restrict__ g,
                                               const float* __restrict__ b, unsigned short* __restrict__ dst,
                                               int stride, int off){
  const int lane = threadIdx.x & 63;
  const int row = blockIdx.x*4 + (threadIdx.x >> 6);
  float4 v = ((const float4*)(X + (size_t)row*256))[lane];
  float mu = waveSum(v.x + v.y + v.z + v.w) * (1.f/256.f);
  float x0 = v.x - mu, x1 = v.y - mu, x2 = v.z - mu, x3 = v.w - mu;
  float var = waveSum(x0*x0 + x1*x1 + x2*x2 + x3*x3) * (1.f/256.f);
  float rs = rsqrtf(var + 1e-5f);
  float4 gv = ((const float4*)g)[lane];
  float4 bv = ((const float4*)b)[lane];
  ushort4 o;
  o.x = f2bf(x0*rs*gv.x + bv.x);
  o.y = f2bf(x1*rs*gv.y + bv.y);
  o.z = f2bf(x2*rs*gv.z + bv.z);
  o.w = f2bf(x3*rs*gv.w + bv.w);
  ((ushort4*)(dst + (size_t)row*stride + off))[lane] = o;
}

__global__ __launch_bounds__(256) void ln_acc(const float* __restrict__ X, const float* __restrict__ g,
                                              const float* __restrict__ b, float* __restrict__ macc, int add){
  const int lane = threadIdx.x & 63;
  const int row = blockIdx.x*4 + (threadIdx.x >> 6);
  float4 v = ((const float4*)(X + (size_t)row*256))[lane];
  float mu = waveSum(v.x + v.y + v.z + v.w) * (1.f/256.f);
  float x0 = v.x - mu, x1 = v.y - mu, x2 = v.z - mu, x3 = v.w - mu;
  float var = waveSum(x0*x0 + x1*x1 + x2*x2 + x3*x3) * (1.f/256.f);
  float rs = rsqrtf(var + 1e-5f);
  float4 gv = ((const float4*)g)[lane];
  float4 bv = ((const float4*)b)[lane];
  float4 y;
  y.x = x0*rs*gv.x + bv.x;
  y.y = x1*rs*gv.y + bv.y;
  y.z = x2*rs*gv.z + bv.z;
  y.w = x3*rs*gv.w + bv.w;
  float4* mp = (float4*)(macc + (size_t)row*256) + lane;
  if (add){
    float4 old = *mp;
    y.x += old.x; y.y += old.y; y.z += old.z; y.w += old.w;
  }
  *mp = y;
}

// ---------- elementwise ----------
__global__ __launch_bounds__(256) void fill_hcat(const float* __restrict__ x, unsigned short* __restrict__ hcat){
  size_t i = (size_t)blockIdx.x*256 + threadIdx.x;
  hcat[(i >> 8)*512 + (i & 255)] = f2bf(x[i]);
}
__global__ __launch_bounds__(256) void xmid_k(const float* __restrict__ x, const float* __restrict__ macc,
                                              float* __restrict__ xmid, unsigned short* __restrict__ hcat){
  size_t i = (size_t)blockIdx.x*256 + threadIdx.x;
  float v = x[i] + 0.5f*macc[i];
  xmid[i] = v;
  hcat[(i >> 8)*512 + (i & 255)] = f2bf(v);
}
__global__ __launch_bounds__(256) void final_k(float* __restrict__ out, const float* __restrict__ macc){
  size_t i = (size_t)blockIdx.x*256 + threadIdx.x;
  out[i] = out[i] + 0.5f*macc[i];
}
__global__ __launch_bounds__(256) void zero_k(float* __restrict__ p, int n){
  int i = blockIdx.x*256 + threadIdx.x;
  if (i < n) p[i] = 0.f;
}

// ---------- orchestration ----------
extern "C" void kernel_launch(void* const* d_in, const int* in_sizes, int n_in,
                              void* d_out, int out_size, void* d_ws, size_t ws_size,
                              hipStream_t stream){
  const float* x   = (const float*)d_in[0];
  const float* src = (const float*)d_in[1];
  const float* Wq  = (const float*)d_in[2];
  const float* Wk  = (const float*)d_in[3];
  const float* Wv  = (const float*)d_in[4];
  const float* Wm  = (const float*)d_in[5];
  const float* W1  = (const float*)d_in[6];
  const float* W2  = (const float*)d_in[7];
  const float* g1  = (const float*)d_in[8];
  const float* b1  = (const float*)d_in[9];
  const float* g2  = (const float*)d_in[10];
  const float* b2  = (const float*)d_in[11];
  float* out = (float*)d_out;

  // ---- workspace layout (~179.5 MB) ----
  char* ws = (char*)d_ws;
  size_t off = 0;
  auto alloc = [&](size_t bytes) -> void* {
    void* p = ws + off;
    off += (bytes + 255) & ~(size_t)255;
    return p;
  };
  unsigned short* qB    = (unsigned short*)alloc((size_t)MROWS*256*2);
  unsigned short* kB    = (unsigned short*)alloc((size_t)MROWS*256*2);
  unsigned short* vB    = (unsigned short*)alloc((size_t)MROWS*256*2);
  unsigned short* hcatB = (unsigned short*)alloc((size_t)MROWS*512*2);
  float* t1   = (float*)alloc((size_t)MROWS*256*4);
  float* macc = (float*)alloc((size_t)MROWS*256*4);
  float* KV4  = (float*)alloc((size_t)4*KVSET*4);
  unsigned short* WqT = (unsigned short*)alloc((size_t)256*256*2);
  unsigned short* WkT = (unsigned short*)alloc((size_t)256*256*2);
  unsigned short* WvT = (unsigned short*)alloc((size_t)256*256*2);
  unsigned short* WmT = (unsigned short*)alloc((size_t)256*256*2);
  unsigned short* W1T = (unsigned short*)alloc((size_t)512*512*2);
  unsigned short* W2T = (unsigned short*)alloc((size_t)256*512*2);
  (void)ws_size; (void)in_sizes; (void)n_in; (void)out_size;

  unsigned short* msgB  = kB;
  unsigned short* hidB  = kB;
  unsigned short* srcbf = (unsigned short*)t1;
  unsigned short* xbf   = srcbf + (size_t)MROWS*256;
  unsigned short* qP    = (unsigned short*)t1;
  unsigned short* kP    = (unsigned short*)macc;
  unsigned short* vP    = kP + (size_t)MROWS*256;
  float* xmid = out;

  const dim3 blk(256);

  // one-time converts
  wconv<<<dim3(256),  blk, 0, stream>>>(Wq, WqT, 8, 256);
  wconv<<<dim3(256),  blk, 0, stream>>>(Wk, WkT, 8, 256);
  wconv<<<dim3(256),  blk, 0, stream>>>(Wv, WvT, 8, 256);
  wconv<<<dim3(256),  blk, 0, stream>>>(Wm, WmT, 8, 256);
  wconv<<<dim3(1024), blk, 0, stream>>>(W1, W1T, 9, 512);
  wconv<<<dim3(512),  blk, 0, stream>>>(W2, W2T, 9, 256);
  conv_bf16<<<dim3(9600), blk, 0, stream>>>(src, srcbf);
  conv_bf16<<<dim3(9600), blk, 0, stream>>>(x,   xbf);

  // projections
  gemm_mfma<unsigned short, false><<<dim3(2,300), blk, 0, stream>>>(xbf,   WqT, qB, MROWS, 256, 256);
  gemm_mfma<unsigned short, false><<<dim3(2,300), blk, 0, stream>>>(srcbf, WkT, kB, MROWS, 256, 256);
  gemm_mfma<unsigned short, false><<<dim3(2,300), blk, 0, stream>>>(srcbf, WvT, vB, MROWS, 256, 256);

  // all-mode stats upfront; permuted k/v in macc space
  zero_k<<<dim3(1056), blk, 0, stream>>>(KV4, 4*KVSET);
  attn_stats<<<dim3(20,8,8), blk, 0, stream>>>(kB, vB, KV4 + 0*KVSET, KV4 + 0*KVSET + 65536);
  permute1<<<dim3(9600,1,2), blk, 0, stream>>>(kB, kP, vB, vP);
  attn_stats<<<dim3(20,8,8), blk, 0, stream>>>(kP, vP, KV4 + 1*KVSET, KV4 + 1*KVSET + 65536);
  permute2<<<dim3(75,8,2),  blk, 0, stream>>>(kB, kP, vB, vP);
  attn_stats<<<dim3(20,8,8), blk, 0, stream>>>(kP, vP, KV4 + 2*KVSET, KV4 + 2*KVSET + 65536);
  permute3<<<dim3(75,8,2),  blk, 0, stream>>>(kB, kP, vB, vP);
  attn_stats<<<dim3(20,8,8), blk, 0, stream>>>(kP, vP, KV4 + 3*KVSET, KV4 + 3*KVSET + 65536);

  fill_hcat<<<dim3(MROWS), blk, 0, stream>>>(x, hcatB);

  auto run_block = [&](int mode, int add){
    const float* KV   = KV4 + (size_t)mode*KVSET;
    const float* Ksum = KV + 65536;
    const unsigned short* qsrc = qB;
    if (mode == 1){ permute1<<<dim3(9600,1,1), blk, 0, stream>>>(qB, qP, nullptr, nullptr); qsrc = qP; }
    else if (mode == 2){ permute2<<<dim3(75,8,1), blk, 0, stream>>>(qB, qP, nullptr, nullptr); qsrc = qP; }
    else if (mode == 3){ permute3<<<dim3(75,8,1), blk, 0, stream>>>(qB, qP, nullptr, nullptr); qsrc = qP; }
    attn_apply<<<dim3(300,BS), blk, 0, stream>>>(qsrc, KV, Ksum, msgB);
    gemm_mfma<float, false><<<dim3(2,300), blk, 0, stream>>>(msgB, WmT, t1, MROWS, 256, 256);
    ln_bf16<<<dim3(9600), blk, 0, stream>>>(t1, g1, b1, hcatB, 512, 256);
    gemm_mfma<unsigned short, true><<<dim3(4,300), blk, 0, stream>>>(hcatB, W1T, hidB, MROWS, 512, 512);
    gemm_mfma<float, false><<<dim3(2,300), blk, 0, stream>>>(hidB, W2T, t1, MROWS, 256, 512);
    ln_acc<<<dim3(9600), blk, 0, stream>>>(t1, g2, b2, macc, add);
  };

  run_block(0, 0);   // m   (identity)
  run_block(1, 1);   // m3  (p13)
  xmid_k<<<dim3(MROWS), blk, 0, stream>>>(x, macc, xmid, hcatB);
  run_block(2, 0);   // m1  (p21)
  run_block(3, 1);   // m2  (p32)
  final_k<<<dim3(MROWS), blk, 0, stream>>>(out, macc);
}